// Round 5
// baseline (2676.202 us; speedup 1.0000x reference)
//
#include <hip/hip_runtime.h>
#include <math.h>

#define HDIM 128

typedef unsigned int uint;
typedef unsigned short ushort;
typedef unsigned long long ull;
typedef __attribute__((ext_vector_type(8))) short short8;
typedef __attribute__((ext_vector_type(4))) float f32x4;

// bf16 helpers (bit-level; bf16->fp32 exact, fp32->bf16 RNE)
__device__ __forceinline__ float bflo(uint u){ return __uint_as_float(u<<16); }
__device__ __forceinline__ float bfhi(uint u){ return __uint_as_float(u&0xffff0000u); }
__device__ __forceinline__ ushort f2bf(float f){
  uint x = __float_as_uint(f);
  return (ushort)((x + 0x7fffu + ((x>>16)&1u)) >> 16);
}
__device__ __forceinline__ uint pack2bf(float a, float b){
  return (uint)f2bf(a) | ((uint)f2bf(b)<<16);
}

// ---------- CSR build ----------
__global__ void k_zero(int* cnt, int* bcur, int n){
  int i = blockIdx.x*256 + threadIdx.x;
  if (i<n) cnt[i]=0;
  if (blockIdx.x==0 && threadIdx.x<8) bcur[threadIdx.x]=0;
}

// phase 1: bin edges by dst-partition (p = d/R, 8 partitions).
// wave-aggregated cursor atomics; records written densely per partition.
__global__ __launch_bounds__(256) void k_bin(const int* __restrict__ src, const int* __restrict__ dst,
                     int2* __restrict__ bins, int* __restrict__ bcur,
                     int e, int R, int cap){
  int lane = threadIdx.x & 63;
  ull ltmask = (1ULL<<lane)-1ULL;
  int stride = gridDim.x*256;
  for (int i = blockIdx.x*256 + threadIdx.x; i < e; i += stride){
    int s = __builtin_nontemporal_load(&src[i]);
    int d = __builtin_nontemporal_load(&dst[i]);
    int p = d / R;
    int slot = 0;
    #pragma unroll
    for (int q=0;q<8;q++){
      ull m = __ballot(p==q);
      if (p==q){
        int rank = __popcll(m & ltmask);
        int leader = (int)__ffsll((long long)m) - 1;
        int b = 0;
        if (lane==leader) b = atomicAdd(&bcur[q], (int)__popcll(m));
        b = __shfl(b, leader);
        slot = b + rank;
      }
    }
    if (slot < cap) bins[(size_t)p*cap + slot] = make_int2(s,d);
  }
}

// phase 2a: degree count, XCD-local (partition p = blockIdx&7 owns cnt slice)
__global__ __launch_bounds__(256) void k_count2(const int2* __restrict__ bins, const int* __restrict__ bcur,
                     int* __restrict__ cnt, int cap){
  int p = blockIdx.x & 7;
  int m = bcur[p];
  int bi = blockIdx.x >> 3;
  int nb = gridDim.x >> 3;
  int stride = nb*256;
  const ull* reg = (const ull*)(bins + (size_t)p*cap);
  for (int i = bi*256 + threadIdx.x; i < m; i += stride){
    ull v = __builtin_nontemporal_load(&reg[i]);
    int d = (int)(v >> 32);
    atomicAdd(&cnt[d], 1);
  }
}

// scan1 also produces dis = rsqrt(deg+1)
__global__ void k_scan1(const int* __restrict__ cnt, int* __restrict__ off, int* __restrict__ bsum,
                        float* __restrict__ dis, int n){
  __shared__ int tmp[256];
  int t = threadIdx.x; int i = blockIdx.x*256 + t;
  int v = (i<n) ? cnt[i] : 0;
  if (i<n) dis[i] = rsqrtf((float)(v+1));
  tmp[t] = v; __syncthreads();
  for (int d=1; d<256; d<<=1){
    int a = (t>=d) ? tmp[t-d] : 0;
    __syncthreads(); tmp[t] += a; __syncthreads();
  }
  if (i<n) off[i] = tmp[t] - v;
  if (t==255) bsum[blockIdx.x] = tmp[255];
}

__global__ void k_scan2(const int* __restrict__ bsum, int* __restrict__ bpre, int nb){
  __shared__ int tmp[512];
  int t = threadIdx.x;
  int v = (t<nb) ? bsum[t] : 0;
  tmp[t] = v; __syncthreads();
  for (int d=1; d<512; d<<=1){
    int a = (t>=d) ? tmp[t-d] : 0;
    __syncthreads(); tmp[t] += a; __syncthreads();
  }
  if (t<nb) bpre[t] = tmp[t] - v;
}

__global__ void k_scan3(int* __restrict__ off, int* __restrict__ cur, const int* __restrict__ bpre, int n){
  int i = blockIdx.x*256 + threadIdx.x;
  if (i<n){ int o = off[i] + bpre[blockIdx.x]; off[i]=o; cur[i]=o; }
}

// phase 2b: scatter into CSR. Partition's working set (1.6MB binned read,
// 1.6MB cw slice, 50KB cur, 400KB dis) fits one XCD L2; no polluting streams.
__global__ __launch_bounds__(256) void k_scatter2(const int2* __restrict__ bins, const int* __restrict__ bcur,
                     const float* __restrict__ dis, int* __restrict__ cur,
                     int2* __restrict__ cw, int cap){
  int p = blockIdx.x & 7;
  int m = bcur[p];
  int bi = blockIdx.x >> 3;
  int nb = gridDim.x >> 3;
  int stride = nb*256;
  const ull* reg = (const ull*)(bins + (size_t)p*cap);
  for (int i = bi*256 + threadIdx.x; i < m; i += stride){
    ull v = __builtin_nontemporal_load(&reg[i]);
    int s = (int)(v & 0xffffffffULL);
    int d = (int)(v >> 32);
    int pos = atomicAdd(&cur[d], 1);
    int2 r; r.x = s; r.y = __float_as_int(dis[s]*dis[d]);
    cw[pos] = r;
  }
}

// ---------- W transpose + bf16: Wt[out][in] ----------
__global__ void k_wt(const float* __restrict__ W, ushort* __restrict__ Wt){
  int idx = blockIdx.x*256 + threadIdx.x;   // 16384 total
  int no = idx>>7, k = idx&127;
  Wt[idx] = f2bf(W[k*HDIM + no]);
}

// ---------- scalar aggregation: s = A_norm * x ----------
__global__ void k_sagg(const float* __restrict__ x, const int* __restrict__ off, const int* __restrict__ cnt,
                       const int2* __restrict__ cw, const float* __restrict__ dis,
                       float* __restrict__ s, int n){
  int i = blockIdx.x*256 + threadIdx.x;
  if (i>=n) return;
  int b = off[i], e = b + cnt[i];
  float di = dis[i];
  float acc = di*di*x[i];
  for (int k=b;k<e;k++){
    int2 v = cw[k];
    acc = fmaf(__int_as_float(v.y), x[v.x], acc);
  }
  s[i] = acc;
}

// h0[i][c] = relu(s[i]*W0[c] + b0[c]) -> bf16 table
__global__ void k_h0(const float* __restrict__ s, const float* __restrict__ W0, const float* __restrict__ b0,
                     uint* __restrict__ h, int n){
  int idx = blockIdx.x*256 + threadIdx.x;
  int i = idx>>5, c4 = idx&31;
  if (i>=n) return;
  float sv = s[i];
  float4 w = ((const float4*)W0)[c4];
  float4 b = ((const float4*)b0)[c4];
  float o0 = fmaxf(fmaf(sv,w.x,b.x),0.f);
  float o1 = fmaxf(fmaf(sv,w.y,b.y),0.f);
  float o2 = fmaxf(fmaf(sv,w.z,b.z),0.f);
  float o3 = fmaxf(fmaf(sv,w.w,b.w),0.f);
  uint2 o; o.x = pack2bf(o0,o1); o.y = pack2bf(o2,o3);
  ((uint2*)(h + (size_t)i*64))[c4] = o;
}

// ---------- wide aggregation: g(bf16) = A_norm * h(bf16) ; one wave per node ----------
__global__ __launch_bounds__(256) void k_wagg(const uint* __restrict__ h, const int* __restrict__ off,
                       const int* __restrict__ cnt, const int2* __restrict__ cw,
                       const float* __restrict__ dis, uint* __restrict__ g, int n){
  int wave = threadIdx.x>>6, lane = threadIdx.x&63;
  int i = blockIdx.x*4 + wave;
  if (i>=n) return;
  int b = off[i], e = b + cnt[i];
  float di = dis[i];
  float w2 = di*di;
  uint su = h[(size_t)i*64 + lane];
  float2 acc; acc.x = w2*bflo(su); acc.y = w2*bfhi(su);
  int k = b;
  for (; k+8<=e; k+=8){
    int2 v[8]; uint u[8];
    #pragma unroll
    for (int j=0;j<8;j++) v[j] = cw[k+j];
    #pragma unroll
    for (int j=0;j<8;j++) u[j] = h[(size_t)v[j].x*64 + lane];
    #pragma unroll
    for (int j=0;j<8;j++){
      float w = __int_as_float(v[j].y);
      acc.x = fmaf(w, bflo(u[j]), acc.x); acc.y = fmaf(w, bfhi(u[j]), acc.y);
    }
  }
  for (; k<e; ++k){
    int2 v = cw[k];
    uint u = h[(size_t)v.x*64 + lane];
    float w = __int_as_float(v.y);
    acc.x = fmaf(w, bflo(u), acc.x); acc.y = fmaf(w, bfhi(u), acc.y);
  }
  g[(size_t)i*64 + lane] = pack2bf(acc.x, acc.y);
}

// ---------- dense via MFMA: h' = relu(g @ W + b), bf16 in/out ----------
__global__ __launch_bounds__(256) void k_mm(const uint* __restrict__ g, const ushort* __restrict__ Wt,
                     const float* __restrict__ b, ushort* __restrict__ h, int n){
  __shared__ uint4 Ws4[2048];   // Wt[128][128] bf16, swizzled, 32KB
  __shared__ uint4 As4[1024];   // g[64][128] bf16, swizzled, 16KB
  int t = threadIdx.x;
  int n0 = blockIdx.x*64;

  const uint4* Wg = (const uint4*)Wt;
  #pragma unroll
  for (int i=0;i<8;i++){
    int c = t + i*256;
    int row = c>>4, slot = c&15;
    Ws4[row*16 + (slot^(row&7))] = Wg[c];
  }
  const uint4* Gg = (const uint4*)g;
  #pragma unroll
  for (int i=0;i<4;i++){
    int c = t + i*256;
    int row = c>>4, slot = c&15;
    uint4 v = make_uint4(0,0,0,0);
    if (n0 + row < n) v = Gg[(size_t)(n0+row)*16 + slot];
    As4[row*16 + (slot^(row&7))] = v;
  }
  __syncthreads();

  int w = t>>6, l = t&63;
  int lr = l&15, lg = l>>4;
  f32x4 acc[8];
  #pragma unroll
  for (int j=0;j<8;j++) acc[j] = (f32x4){0.f,0.f,0.f,0.f};

  float bv[8];
  #pragma unroll
  for (int j=0;j<8;j++) bv[j] = b[16*j + lr];

  #pragma unroll
  for (int s=0;s<4;s++){
    short8 a = *(const short8*)&As4[(16*w + lr)*16 + ((4*s + lg)^(lr&7))];
    #pragma unroll
    for (int j=0;j<8;j++){
      short8 bb = *(const short8*)&Ws4[(16*j + lr)*16 + ((4*s + lg)^(lr&7))];
      acc[j] = __builtin_amdgcn_mfma_f32_16x16x32_bf16(a, bb, acc[j], 0, 0, 0);
    }
  }

  #pragma unroll
  for (int j=0;j<8;j++){
    int col = 16*j + lr;
    #pragma unroll
    for (int q=0;q<4;q++){
      int node = n0 + 16*w + lg*4 + q;
      if (node < n){
        float v = fmaxf(acc[j][q] + bv[j], 0.f);
        h[(size_t)node*HDIM + col] = f2bf(v);
      }
    }
  }
}

// ---------- z[i] = h2(bf16)[i] . Wo ; one wave per node, shuffle reduce ----------
__global__ __launch_bounds__(256) void k_z(const uint* __restrict__ h, const float* __restrict__ Wo,
                    float* __restrict__ z, int n){
  int wave = threadIdx.x>>6, lane = threadIdx.x&63;
  int i = blockIdx.x*4 + wave;
  if (i>=n) return;
  uint u = h[(size_t)i*64 + lane];
  float2 wv = ((const float2*)Wo)[lane];
  float v = bflo(u)*wv.x + bfhi(u)*wv.y;
  #pragma unroll
  for (int o=32;o>0;o>>=1) v += __shfl_xor(v,o);
  if (lane==0) z[i]=v;
}

// ---------- y[i] = sigmoid(A_norm z + bo) ----------
__global__ void k_final(const float* __restrict__ z, const int* __restrict__ off, const int* __restrict__ cnt,
                        const int2* __restrict__ cw, const float* __restrict__ dis,
                        const float* __restrict__ bo, float* __restrict__ y, int n){
  int i = blockIdx.x*256 + threadIdx.x;
  if (i>=n) return;
  int b = off[i], e = b + cnt[i];
  float di = dis[i];
  float acc = di*di*z[i];
  for (int k=b;k<e;k++){
    int2 v = cw[k];
    acc = fmaf(__int_as_float(v.y), z[v.x], acc);
  }
  acc += bo[0];
  y[i] = 1.f/(1.f + expf(-acc));
}

extern "C" void kernel_launch(void* const* d_in, const int* in_sizes, int n_in,
                              void* d_out, int out_size, void* d_ws, size_t ws_size,
                              hipStream_t stream){
  const float* x  = (const float*)d_in[0];
  const int*   ei = (const int*)d_in[1];
  const float* W0 = (const float*)d_in[2];
  const float* b0 = (const float*)d_in[3];
  const float* W1 = (const float*)d_in[4];
  const float* b1 = (const float*)d_in[5];
  const float* W2 = (const float*)d_in[6];
  const float* b2 = (const float*)d_in[7];
  const float* Wo = (const float*)d_in[8];
  const float* bo = (const float*)d_in[9];
  int n = in_sizes[0];
  int e = in_sizes[1]/2;
  const int* src = ei;
  const int* dst = ei + e;
  float* y = (float*)d_out;

  int R   = (n + 7) >> 3;           // partition size (dst range per XCD)
  int cap = e/8 + 16384;            // per-partition bin capacity (~38 sigma slack)

  char* p = (char*)d_ws;
  auto alloc = [&](size_t bytes)->void*{ void* r=p; p += (bytes+255)&~(size_t)255; return r; };
  int*    cnt  = (int*)   alloc((size_t)n*4);
  int*    off  = (int*)   alloc((size_t)n*4);
  int*    cur  = (int*)   alloc((size_t)n*4);
  int*    bsum = (int*)   alloc(512*4);
  int*    bpre = (int*)   alloc(512*4);
  int*    bcur = (int*)   alloc(8*4);
  float*  dis  = (float*) alloc((size_t)n*4);
  float*  sb   = (float*) alloc((size_t)n*4);
  float*  zb   = (float*) alloc((size_t)n*4);
  ushort* Wt1  = (ushort*)alloc((size_t)HDIM*HDIM*2);
  ushort* Wt2  = (ushort*)alloc((size_t)HDIM*HDIM*2);
  int2*   cw   = (int2*)  alloc((size_t)e*8);
  int2*   bins = (int2*)  alloc((size_t)cap*8*8);
  uint*   hb0  = (uint*)  alloc((size_t)n*64*4);
  uint*   hb1  = (uint*)  alloc((size_t)n*64*4);
  uint*   gbuf = (uint*)  alloc((size_t)n*64*4);

  int nb = (n+255)/256;
  int mb = (n+63)/64;

  k_zero    <<<nb,256,0,stream>>>(cnt,bcur,n);
  k_bin     <<<512,256,0,stream>>>(src,dst,bins,bcur,e,R,cap);
  k_count2  <<<512,256,0,stream>>>(bins,bcur,cnt,cap);
  k_scan1   <<<nb,256,0,stream>>>(cnt,off,bsum,dis,n);
  k_scan2   <<<1,512,0,stream>>>(bsum,bpre,nb);
  k_scan3   <<<nb,256,0,stream>>>(off,cur,bpre,n);
  k_scatter2<<<512,256,0,stream>>>(bins,bcur,dis,cur,cw,cap);
  k_wt      <<<64,256,0,stream>>>(W1,Wt1);
  k_wt      <<<64,256,0,stream>>>(W2,Wt2);

  k_sagg <<<nb,256,0,stream>>>(x,off,cnt,cw,dis,sb,n);
  k_h0   <<<(n*32+255)/256,256,0,stream>>>(sb,W0,b0,hb0,n);

  k_wagg <<<(n+3)/4,256,0,stream>>>(hb0,off,cnt,cw,dis,gbuf,n);
  k_mm   <<<mb,256,0,stream>>>(gbuf,Wt1,b1,(ushort*)hb1,n);

  k_wagg <<<(n+3)/4,256,0,stream>>>(hb1,off,cnt,cw,dis,gbuf,n);
  k_mm   <<<mb,256,0,stream>>>(gbuf,Wt2,b2,(ushort*)hb0,n);

  k_z    <<<(n+3)/4,256,0,stream>>>(hb0,Wo,zb,n);
  k_final<<<nb,256,0,stream>>>(zb,off,cnt,cw,dis,bo,y,n);
}

// Round 6
// 413.479 us; speedup vs baseline: 6.4724x; 6.4724x over previous
//
#include <hip/hip_runtime.h>
#include <math.h>

#define HDIM 128
#define BINB 512   // blocks in binning grid (must match launches)

typedef unsigned int uint;
typedef unsigned short ushort;
typedef unsigned long long ull;
typedef __attribute__((ext_vector_type(8))) short short8;
typedef __attribute__((ext_vector_type(4))) float f32x4;

// bf16 helpers (bit-level; bf16->fp32 exact, fp32->bf16 RNE)
__device__ __forceinline__ float bflo(uint u){ return __uint_as_float(u<<16); }
__device__ __forceinline__ float bfhi(uint u){ return __uint_as_float(u&0xffff0000u); }
__device__ __forceinline__ ushort f2bf(float f){
  uint x = __float_as_uint(f);
  return (ushort)((x + 0x7fffu + ((x>>16)&1u)) >> 16);
}
__device__ __forceinline__ uint pack2bf(float a, float b){
  return (uint)f2bf(a) | ((uint)f2bf(b)<<16);
}

// ---------- CSR build ----------
__global__ void k_zero(int* cnt, int n){
  int i = blockIdx.x*256 + threadIdx.x;
  if (i<n) cnt[i]=0;
}

// pass A: per-block partition histogram (LDS atomics only) + per-node degree
__global__ __launch_bounds__(256) void k_bcnt(const int* __restrict__ src, const int* __restrict__ dst,
                      int* __restrict__ bh, int* __restrict__ cnt, int e, int R){
  __shared__ int hist[8];
  int t = threadIdx.x;
  if (t<8) hist[t]=0;
  __syncthreads();
  int stride = BINB*256;
  for (int i = blockIdx.x*256 + t; i < e; i += stride){
    int d = __builtin_nontemporal_load(&dst[i]);
    atomicAdd(&hist[d/R], 1);
    atomicAdd(&cnt[d], 1);
  }
  __syncthreads();
  if (t<8) bh[t*BINB + blockIdx.x] = hist[t];
}

// pass A.5: exclusive scan of 8*BINB block-partition counts (partition-major)
__global__ __launch_bounds__(512) void k_bscan(const int* __restrict__ bh, int* __restrict__ bbase,
                       int* __restrict__ pstart, int e){
  __shared__ int part[512];
  int t = threadIdx.x;
  int v[8]; int s = 0;
  #pragma unroll
  for (int j=0;j<8;j++){ int x = bh[t*8+j]; v[j] = s; s += x; }
  part[t] = s; __syncthreads();
  for (int d=1; d<512; d<<=1){
    int a = (t>=d) ? part[t-d] : 0;
    __syncthreads(); part[t] += a; __syncthreads();
  }
  int base = (t>0) ? part[t-1] : 0;
  #pragma unroll
  for (int j=0;j<8;j++) bbase[t*8+j] = base + v[j];
  if ((t&63)==0) pstart[t>>6] = base + v[0];   // start of partition t/64
  if (t==0) pstart[8] = e;
}

// pass B: re-read edges, write records to exact per-(block,partition) offsets.
// No global atomics; dense sequential ranges -> full-line writes.
__global__ __launch_bounds__(256) void k_bin2(const int* __restrict__ src, const int* __restrict__ dst,
                      const int* __restrict__ bbase, int2* __restrict__ bins, int e, int R){
  __shared__ int lcur[8];
  int t = threadIdx.x;
  if (t<8) lcur[t] = bbase[t*BINB + blockIdx.x];
  __syncthreads();
  int stride = BINB*256;
  for (int i = blockIdx.x*256 + t; i < e; i += stride){
    int s = __builtin_nontemporal_load(&src[i]);
    int d = __builtin_nontemporal_load(&dst[i]);
    int pos = atomicAdd(&lcur[d/R], 1);
    bins[pos] = make_int2(s,d);
  }
}

// scan1 also produces dis = rsqrt(deg+1)
__global__ void k_scan1(const int* __restrict__ cnt, int* __restrict__ off, int* __restrict__ bsum,
                        float* __restrict__ dis, int n){
  __shared__ int tmp[256];
  int t = threadIdx.x; int i = blockIdx.x*256 + t;
  int v = (i<n) ? cnt[i] : 0;
  if (i<n) dis[i] = rsqrtf((float)(v+1));
  tmp[t] = v; __syncthreads();
  for (int d=1; d<256; d<<=1){
    int a = (t>=d) ? tmp[t-d] : 0;
    __syncthreads(); tmp[t] += a; __syncthreads();
  }
  if (i<n) off[i] = tmp[t] - v;
  if (t==255) bsum[blockIdx.x] = tmp[255];
}

__global__ void k_scan2(const int* __restrict__ bsum, int* __restrict__ bpre, int nb){
  __shared__ int tmp[512];
  int t = threadIdx.x;
  int v = (t<nb) ? bsum[t] : 0;
  tmp[t] = v; __syncthreads();
  for (int d=1; d<512; d<<=1){
    int a = (t>=d) ? tmp[t-d] : 0;
    __syncthreads(); tmp[t] += a; __syncthreads();
  }
  if (t<nb) bpre[t] = tmp[t] - v;
}

__global__ void k_scan3(int* __restrict__ off, int* __restrict__ cur, const int* __restrict__ bpre, int n){
  int i = blockIdx.x*256 + threadIdx.x;
  if (i<n){ int o = off[i] + bpre[blockIdx.x]; off[i]=o; cur[i]=o; }
}

// scatter into CSR. Partition p=blockIdx&7: streams its contiguous bin segment
// (nontemporal), scatters into its 1.6MB cw slice + 50KB cur -> XCD-L2-resident.
__global__ __launch_bounds__(256) void k_scatter2(const int2* __restrict__ bins, const int* __restrict__ pstart,
                     const float* __restrict__ dis, int* __restrict__ cur,
                     int2* __restrict__ cw){
  int p = blockIdx.x & 7;
  int lo = pstart[p], hi = pstart[p+1];
  int bi = blockIdx.x >> 3;
  int nb = gridDim.x >> 3;
  int stride = nb*256;
  const ull* reg = (const ull*)bins;
  for (int i = lo + bi*256 + threadIdx.x; i < hi; i += stride){
    ull v = __builtin_nontemporal_load(&reg[i]);
    int s = (int)(v & 0xffffffffULL);
    int d = (int)(v >> 32);
    int pos = atomicAdd(&cur[d], 1);
    int2 r; r.x = s; r.y = __float_as_int(dis[s]*dis[d]);
    cw[pos] = r;
  }
}

// ---------- W transpose + bf16: Wt[out][in] ----------
__global__ void k_wt(const float* __restrict__ W, ushort* __restrict__ Wt){
  int idx = blockIdx.x*256 + threadIdx.x;   // 16384 total
  int no = idx>>7, k = idx&127;
  Wt[idx] = f2bf(W[k*HDIM + no]);
}

// ---------- scalar aggregation: s = A_norm * x ----------
__global__ void k_sagg(const float* __restrict__ x, const int* __restrict__ off, const int* __restrict__ cnt,
                       const int2* __restrict__ cw, const float* __restrict__ dis,
                       float* __restrict__ s, int n){
  int i = blockIdx.x*256 + threadIdx.x;
  if (i>=n) return;
  int b = off[i], e = b + cnt[i];
  float di = dis[i];
  float acc = di*di*x[i];
  for (int k=b;k<e;k++){
    int2 v = cw[k];
    acc = fmaf(__int_as_float(v.y), x[v.x], acc);
  }
  s[i] = acc;
}

// h0[i][c] = relu(s[i]*W0[c] + b0[c]) -> bf16 table
__global__ void k_h0(const float* __restrict__ s, const float* __restrict__ W0, const float* __restrict__ b0,
                     uint* __restrict__ h, int n){
  int idx = blockIdx.x*256 + threadIdx.x;
  int i = idx>>5, c4 = idx&31;
  if (i>=n) return;
  float sv = s[i];
  float4 w = ((const float4*)W0)[c4];
  float4 b = ((const float4*)b0)[c4];
  float o0 = fmaxf(fmaf(sv,w.x,b.x),0.f);
  float o1 = fmaxf(fmaf(sv,w.y,b.y),0.f);
  float o2 = fmaxf(fmaf(sv,w.z,b.z),0.f);
  float o3 = fmaxf(fmaf(sv,w.w,b.w),0.f);
  uint2 o; o.x = pack2bf(o0,o1); o.y = pack2bf(o2,o3);
  ((uint2*)(h + (size_t)i*64))[c4] = o;
}

// ---------- wide aggregation: g(bf16) = A_norm * h(bf16) ; one wave per node ----------
__global__ __launch_bounds__(256) void k_wagg(const uint* __restrict__ h, const int* __restrict__ off,
                       const int* __restrict__ cnt, const int2* __restrict__ cw,
                       const float* __restrict__ dis, uint* __restrict__ g, int n){
  int wave = threadIdx.x>>6, lane = threadIdx.x&63;
  int i = blockIdx.x*4 + wave;
  if (i>=n) return;
  int b = off[i], e = b + cnt[i];
  float di = dis[i];
  float w2 = di*di;
  uint su = h[(size_t)i*64 + lane];
  float2 acc; acc.x = w2*bflo(su); acc.y = w2*bfhi(su);
  int k = b;
  for (; k+8<=e; k+=8){
    int2 v[8]; uint u[8];
    #pragma unroll
    for (int j=0;j<8;j++) v[j] = cw[k+j];
    #pragma unroll
    for (int j=0;j<8;j++) u[j] = h[(size_t)v[j].x*64 + lane];
    #pragma unroll
    for (int j=0;j<8;j++){
      float w = __int_as_float(v[j].y);
      acc.x = fmaf(w, bflo(u[j]), acc.x); acc.y = fmaf(w, bfhi(u[j]), acc.y);
    }
  }
  for (; k<e; ++k){
    int2 v = cw[k];
    uint u = h[(size_t)v.x*64 + lane];
    float w = __int_as_float(v.y);
    acc.x = fmaf(w, bflo(u), acc.x); acc.y = fmaf(w, bfhi(u), acc.y);
  }
  g[(size_t)i*64 + lane] = pack2bf(acc.x, acc.y);
}

// ---------- dense via MFMA: h' = relu(g @ W + b), bf16 in/out ----------
__global__ __launch_bounds__(256) void k_mm(const uint* __restrict__ g, const ushort* __restrict__ Wt,
                     const float* __restrict__ b, ushort* __restrict__ h, int n){
  __shared__ uint4 Ws4[2048];   // Wt[128][128] bf16, swizzled, 32KB
  __shared__ uint4 As4[1024];   // g[64][128] bf16, swizzled, 16KB
  int t = threadIdx.x;
  int n0 = blockIdx.x*64;

  const uint4* Wg = (const uint4*)Wt;
  #pragma unroll
  for (int i=0;i<8;i++){
    int c = t + i*256;
    int row = c>>4, slot = c&15;
    Ws4[row*16 + (slot^(row&7))] = Wg[c];
  }
  const uint4* Gg = (const uint4*)g;
  #pragma unroll
  for (int i=0;i<4;i++){
    int c = t + i*256;
    int row = c>>4, slot = c&15;
    uint4 v = make_uint4(0,0,0,0);
    if (n0 + row < n) v = Gg[(size_t)(n0+row)*16 + slot];
    As4[row*16 + (slot^(row&7))] = v;
  }
  __syncthreads();

  int w = t>>6, l = t&63;
  int lr = l&15, lg = l>>4;
  f32x4 acc[8];
  #pragma unroll
  for (int j=0;j<8;j++) acc[j] = (f32x4){0.f,0.f,0.f,0.f};

  float bv[8];
  #pragma unroll
  for (int j=0;j<8;j++) bv[j] = b[16*j + lr];

  #pragma unroll
  for (int s=0;s<4;s++){
    short8 a = *(const short8*)&As4[(16*w + lr)*16 + ((4*s + lg)^(lr&7))];
    #pragma unroll
    for (int j=0;j<8;j++){
      short8 bb = *(const short8*)&Ws4[(16*j + lr)*16 + ((4*s + lg)^(lr&7))];
      acc[j] = __builtin_amdgcn_mfma_f32_16x16x32_bf16(a, bb, acc[j], 0, 0, 0);
    }
  }

  #pragma unroll
  for (int j=0;j<8;j++){
    int col = 16*j + lr;
    #pragma unroll
    for (int q=0;q<4;q++){
      int node = n0 + 16*w + lg*4 + q;
      if (node < n){
        float v = fmaxf(acc[j][q] + bv[j], 0.f);
        h[(size_t)node*HDIM + col] = f2bf(v);
      }
    }
  }
}

// ---------- z[i] = h2(bf16)[i] . Wo ; one wave per node, shuffle reduce ----------
__global__ __launch_bounds__(256) void k_z(const uint* __restrict__ h, const float* __restrict__ Wo,
                    float* __restrict__ z, int n){
  int wave = threadIdx.x>>6, lane = threadIdx.x&63;
  int i = blockIdx.x*4 + wave;
  if (i>=n) return;
  uint u = h[(size_t)i*64 + lane];
  float2 wv = ((const float2*)Wo)[lane];
  float v = bflo(u)*wv.x + bfhi(u)*wv.y;
  #pragma unroll
  for (int o=32;o>0;o>>=1) v += __shfl_xor(v,o);
  if (lane==0) z[i]=v;
}

// ---------- y[i] = sigmoid(A_norm z + bo) ----------
__global__ void k_final(const float* __restrict__ z, const int* __restrict__ off, const int* __restrict__ cnt,
                        const int2* __restrict__ cw, const float* __restrict__ dis,
                        const float* __restrict__ bo, float* __restrict__ y, int n){
  int i = blockIdx.x*256 + threadIdx.x;
  if (i>=n) return;
  int b = off[i], e = b + cnt[i];
  float di = dis[i];
  float acc = di*di*z[i];
  for (int k=b;k<e;k++){
    int2 v = cw[k];
    acc = fmaf(__int_as_float(v.y), z[v.x], acc);
  }
  acc += bo[0];
  y[i] = 1.f/(1.f + expf(-acc));
}

extern "C" void kernel_launch(void* const* d_in, const int* in_sizes, int n_in,
                              void* d_out, int out_size, void* d_ws, size_t ws_size,
                              hipStream_t stream){
  const float* x  = (const float*)d_in[0];
  const int*   ei = (const int*)d_in[1];
  const float* W0 = (const float*)d_in[2];
  const float* b0 = (const float*)d_in[3];
  const float* W1 = (const float*)d_in[4];
  const float* b1 = (const float*)d_in[5];
  const float* W2 = (const float*)d_in[6];
  const float* b2 = (const float*)d_in[7];
  const float* Wo = (const float*)d_in[8];
  const float* bo = (const float*)d_in[9];
  int n = in_sizes[0];
  int e = in_sizes[1]/2;
  const int* src = ei;
  const int* dst = ei + e;
  float* y = (float*)d_out;

  int R = (n + 7) >> 3;             // partition size (dst range per XCD)

  char* p = (char*)d_ws;
  auto alloc = [&](size_t bytes)->void*{ void* r=p; p += (bytes+255)&~(size_t)255; return r; };
  int*    cnt  = (int*)   alloc((size_t)n*4);
  int*    off  = (int*)   alloc((size_t)n*4);
  int*    cur  = (int*)   alloc((size_t)n*4);
  int*    bsum = (int*)   alloc(512*4);
  int*    bpre = (int*)   alloc(512*4);
  int*    bh   = (int*)   alloc((size_t)8*BINB*4);
  int*    bbase= (int*)   alloc((size_t)8*BINB*4);
  int*    pst  = (int*)   alloc(16*4);
  float*  dis  = (float*) alloc((size_t)n*4);
  float*  sb   = (float*) alloc((size_t)n*4);
  float*  zb   = (float*) alloc((size_t)n*4);
  ushort* Wt1  = (ushort*)alloc((size_t)HDIM*HDIM*2);
  ushort* Wt2  = (ushort*)alloc((size_t)HDIM*HDIM*2);
  int2*   cw   = (int2*)  alloc((size_t)e*8);
  int2*   bins = (int2*)  alloc((size_t)e*8);
  uint*   hb0  = (uint*)  alloc((size_t)n*64*4);
  uint*   hb1  = (uint*)  alloc((size_t)n*64*4);
  uint*   gbuf = (uint*)  alloc((size_t)n*64*4);

  int nb = (n+255)/256;
  int mb = (n+63)/64;

  k_zero    <<<nb,256,0,stream>>>(cnt,n);
  k_bcnt    <<<BINB,256,0,stream>>>(src,dst,bh,cnt,e,R);
  k_bscan   <<<1,512,0,stream>>>(bh,bbase,pst,e);
  k_scan1   <<<nb,256,0,stream>>>(cnt,off,bsum,dis,n);
  k_scan2   <<<1,512,0,stream>>>(bsum,bpre,nb);
  k_scan3   <<<nb,256,0,stream>>>(off,cur,bpre,n);
  k_bin2    <<<BINB,256,0,stream>>>(src,dst,bbase,bins,e,R);
  k_scatter2<<<512,256,0,stream>>>(bins,pst,dis,cur,cw);
  k_wt      <<<64,256,0,stream>>>(W1,Wt1);
  k_wt      <<<64,256,0,stream>>>(W2,Wt2);

  k_sagg <<<nb,256,0,stream>>>(x,off,cnt,cw,dis,sb,n);
  k_h0   <<<(n*32+255)/256,256,0,stream>>>(sb,W0,b0,hb0,n);

  k_wagg <<<(n+3)/4,256,0,stream>>>(hb0,off,cnt,cw,dis,gbuf,n);
  k_mm   <<<mb,256,0,stream>>>(gbuf,Wt1,b1,(ushort*)hb1,n);

  k_wagg <<<(n+3)/4,256,0,stream>>>(hb1,off,cnt,cw,dis,gbuf,n);
  k_mm   <<<mb,256,0,stream>>>(gbuf,Wt2,b2,(ushort*)hb0,n);

  k_z    <<<(n+3)/4,256,0,stream>>>(hb0,Wo,zb,n);
  k_final<<<nb,256,0,stream>>>(zb,off,cnt,cw,dis,bo,y,n);
}

// Round 7
// 387.007 us; speedup vs baseline: 6.9151x; 1.0684x over previous
//
#include <hip/hip_runtime.h>
#include <math.h>

#define HDIM 128
#define BINB 512   // blocks in binning grid (must match launches)

typedef unsigned int uint;
typedef unsigned short ushort;
typedef unsigned long long ull;
typedef __attribute__((ext_vector_type(8))) short short8;
typedef __attribute__((ext_vector_type(4))) float f32x4;

// bf16 helpers (bit-level; bf16->fp32 exact, fp32->bf16 RNE)
__device__ __forceinline__ float bflo(uint u){ return __uint_as_float(u<<16); }
__device__ __forceinline__ float bfhi(uint u){ return __uint_as_float(u&0xffff0000u); }
__device__ __forceinline__ ushort f2bf(float f){
  uint x = __float_as_uint(f);
  return (ushort)((x + 0x7fffu + ((x>>16)&1u)) >> 16);
}
__device__ __forceinline__ uint pack2bf(float a, float b){
  return (uint)f2bf(a) | ((uint)f2bf(b)<<16);
}

// ---------- prep: zero cnt + transpose W1,W2 to bf16 ----------
__global__ void k_prep(int* __restrict__ cnt, const float* __restrict__ W1, const float* __restrict__ W2,
                       ushort* __restrict__ Wt1, ushort* __restrict__ Wt2, int n){
  int i = blockIdx.x*256 + threadIdx.x;
  if (i<n) cnt[i]=0;
  if (i<HDIM*HDIM){
    int no = i>>7, k = i&127;
    Wt1[i] = f2bf(W1[k*HDIM+no]);
    Wt2[i] = f2bf(W2[k*HDIM+no]);
  }
}

// pass A: per-block partition histogram (LDS atomics only)
__global__ __launch_bounds__(256) void k_bcnt(const int* __restrict__ dst, int* __restrict__ bh,
                                              int e, int R){
  __shared__ int hist[8];
  int t = threadIdx.x;
  if (t<8) hist[t]=0;
  __syncthreads();
  int stride = BINB*256;
  for (int i = blockIdx.x*256 + t; i < e; i += stride){
    int d = __builtin_nontemporal_load(&dst[i]);
    atomicAdd(&hist[d/R], 1);
  }
  __syncthreads();
  if (t<8) bh[t*BINB + blockIdx.x] = hist[t];
}

// pass A.5: exclusive scan of 8*BINB block-partition counts (partition-major)
__global__ __launch_bounds__(512) void k_bscan(const int* __restrict__ bh, int* __restrict__ bbase,
                       int* __restrict__ pstart, int e){
  __shared__ int part[512];
  int t = threadIdx.x;
  int v[8]; int s = 0;
  #pragma unroll
  for (int j=0;j<8;j++){ int x = bh[t*8+j]; v[j] = s; s += x; }
  part[t] = s; __syncthreads();
  for (int d=1; d<512; d<<=1){
    int a = (t>=d) ? part[t-d] : 0;
    __syncthreads(); part[t] += a; __syncthreads();
  }
  int base = (t>0) ? part[t-1] : 0;
  #pragma unroll
  for (int j=0;j<8;j++) bbase[t*8+j] = base + v[j];
  if ((t&63)==0) pstart[t>>6] = base + v[0];
  if (t==0) pstart[8] = e;
}

// pass B: write (src,dst) records to exact per-(block,partition) offsets
__global__ __launch_bounds__(256) void k_bin2(const int* __restrict__ src, const int* __restrict__ dst,
                      const int* __restrict__ bbase, int2* __restrict__ bins, int e, int R){
  __shared__ int lcur[8];
  int t = threadIdx.x;
  if (t<8) lcur[t] = bbase[t*BINB + blockIdx.x];
  __syncthreads();
  int stride = BINB*256;
  for (int i = blockIdx.x*256 + t; i < e; i += stride){
    int s = __builtin_nontemporal_load(&src[i]);
    int d = __builtin_nontemporal_load(&dst[i]);
    int pos = atomicAdd(&lcur[d/R], 1);
    bins[pos] = make_int2(s,d);
  }
}

// degree count from bins: partition p=blockIdx&7 -> atomics on XCD-local cnt slice
__global__ __launch_bounds__(256) void k_count2(const int2* __restrict__ bins, const int* __restrict__ pstart,
                     int* __restrict__ cnt){
  int p = blockIdx.x & 7;
  int lo = pstart[p], hi = pstart[p+1];
  int bi = blockIdx.x >> 3;
  int nb = gridDim.x >> 3;
  int stride = nb*256;
  const ull* reg = (const ull*)bins;
  for (int i = lo + bi*256 + threadIdx.x; i < hi; i += stride){
    ull v = __builtin_nontemporal_load(&reg[i]);
    int d = (int)(v >> 32);
    atomicAdd(&cnt[d], 1);
  }
}

// scan1 also produces dis = rsqrt(deg+1) and xs = dis*x
__global__ void k_scan1(const int* __restrict__ cnt, int* __restrict__ off, int* __restrict__ bsum,
                        float* __restrict__ dis, float* __restrict__ xs, const float* __restrict__ x, int n){
  __shared__ int tmp[256];
  int t = threadIdx.x; int i = blockIdx.x*256 + t;
  int v = (i<n) ? cnt[i] : 0;
  if (i<n){ float d = rsqrtf((float)(v+1)); dis[i] = d; xs[i] = d*x[i]; }
  tmp[t] = v; __syncthreads();
  for (int d=1; d<256; d<<=1){
    int a = (t>=d) ? tmp[t-d] : 0;
    __syncthreads(); tmp[t] += a; __syncthreads();
  }
  if (i<n) off[i] = tmp[t] - v;
  if (t==255) bsum[blockIdx.x] = tmp[255];
}

__global__ void k_scan2(const int* __restrict__ bsum, int* __restrict__ bpre, int nb){
  __shared__ int tmp[512];
  int t = threadIdx.x;
  int v = (t<nb) ? bsum[t] : 0;
  tmp[t] = v; __syncthreads();
  for (int d=1; d<512; d<<=1){
    int a = (t>=d) ? tmp[t-d] : 0;
    __syncthreads(); tmp[t] += a; __syncthreads();
  }
  if (t<nb) bpre[t] = tmp[t] - v;
}

__global__ void k_scan3(int* __restrict__ off, int* __restrict__ cur, const int* __restrict__ bpre, int n){
  int i = blockIdx.x*256 + threadIdx.x;
  if (i<n){ int o = off[i] + bpre[blockIdx.x]; off[i]=o; cur[i]=o; }
}

// scatter src-only records into CSR (4B); partition slice XCD-L2-resident
__global__ __launch_bounds__(256) void k_scatter2(const int2* __restrict__ bins, const int* __restrict__ pstart,
                     int* __restrict__ cur, int* __restrict__ cw){
  int p = blockIdx.x & 7;
  int lo = pstart[p], hi = pstart[p+1];
  int bi = blockIdx.x >> 3;
  int nb = gridDim.x >> 3;
  int stride = nb*256;
  const ull* reg = (const ull*)bins;
  for (int i = lo + bi*256 + threadIdx.x; i < hi; i += stride){
    ull v = __builtin_nontemporal_load(&reg[i]);
    int s = (int)(v & 0xffffffffULL);
    int d = (int)(v >> 32);
    int pos = atomicAdd(&cur[d], 1);
    cw[pos] = s;
  }
}

// ---------- scalar aggregation: s_i = dis_i*(xs_i + sum xs[src]) ----------
__global__ void k_sagg(const float* __restrict__ xs, const float* __restrict__ dis,
                       const int* __restrict__ off, const int* __restrict__ cnt,
                       const int* __restrict__ cw, float* __restrict__ s, int n){
  int i = blockIdx.x*256 + threadIdx.x;
  if (i>=n) return;
  int b = off[i], e = b + cnt[i];
  float acc = xs[i];
  int k = b;
  for (; k+4<=e; k+=4){
    int s0=cw[k], s1=cw[k+1], s2=cw[k+2], s3=cw[k+3];
    float a0=xs[s0], a1=xs[s1], a2=xs[s2], a3=xs[s3];
    acc += (a0+a1) + (a2+a3);
  }
  for (; k<e; ++k) acc += xs[cw[k]];
  s[i] = dis[i]*acc;
}

// hs0[i][c] = dis_i * relu(s_i*W0[c] + b0[c]) -> bf16 table
__global__ void k_h0(const float* __restrict__ s, const float* __restrict__ dis,
                     const float* __restrict__ W0, const float* __restrict__ b0,
                     uint* __restrict__ h, int n){
  int idx = blockIdx.x*256 + threadIdx.x;
  int i = idx>>5, c4 = idx&31;
  if (i>=n) return;
  float sv = s[i], dv = dis[i];
  float4 w = ((const float4*)W0)[c4];
  float4 b = ((const float4*)b0)[c4];
  float o0 = dv*fmaxf(fmaf(sv,w.x,b.x),0.f);
  float o1 = dv*fmaxf(fmaf(sv,w.y,b.y),0.f);
  float o2 = dv*fmaxf(fmaf(sv,w.z,b.z),0.f);
  float o3 = dv*fmaxf(fmaf(sv,w.w,b.w),0.f);
  uint2 o; o.x = pack2bf(o0,o1); o.y = pack2bf(o2,o3);
  ((uint2*)(h + (size_t)i*64))[c4] = o;
}

// ---------- wide aggregation: g_i = dis_i*(hs_i + sum hs[src]) ----------
__global__ __launch_bounds__(256) void k_wagg(const uint* __restrict__ h, const int* __restrict__ off,
                       const int* __restrict__ cnt, const int* __restrict__ cw,
                       const float* __restrict__ dis, uint* __restrict__ g, int n){
  int wave = threadIdx.x>>6, lane = threadIdx.x&63;
  int i = blockIdx.x*4 + wave;
  if (i>=n) return;
  int b = off[i], e = b + cnt[i];
  uint su = h[(size_t)i*64 + lane];
  float2 acc; acc.x = bflo(su); acc.y = bfhi(su);
  int k = b;
  for (; k+8<=e; k+=8){
    int v[8]; uint u[8];
    #pragma unroll
    for (int j=0;j<8;j++) v[j] = cw[k+j];
    #pragma unroll
    for (int j=0;j<8;j++) u[j] = h[(size_t)v[j]*64 + lane];
    #pragma unroll
    for (int j=0;j<8;j++){
      acc.x += bflo(u[j]); acc.y += bfhi(u[j]);
    }
  }
  for (; k<e; ++k){
    uint u = h[(size_t)cw[k]*64 + lane];
    acc.x += bflo(u); acc.y += bfhi(u);
  }
  float dv = dis[i];
  g[(size_t)i*64 + lane] = pack2bf(dv*acc.x, dv*acc.y);
}

// ---------- dense via MFMA: hs' = dis * relu(g @ W + b), bf16 in/out ----------
__global__ __launch_bounds__(256) void k_mm(const uint* __restrict__ g, const ushort* __restrict__ Wt,
                     const float* __restrict__ b, const float* __restrict__ dis,
                     ushort* __restrict__ h, int n){
  __shared__ uint4 Ws4[2048];   // Wt[128][128] bf16, swizzled, 32KB
  __shared__ uint4 As4[1024];   // g[64][128] bf16, swizzled, 16KB
  int t = threadIdx.x;
  int n0 = blockIdx.x*64;

  const uint4* Wg = (const uint4*)Wt;
  #pragma unroll
  for (int i=0;i<8;i++){
    int c = t + i*256;
    int row = c>>4, slot = c&15;
    Ws4[row*16 + (slot^(row&7))] = Wg[c];
  }
  const uint4* Gg = (const uint4*)g;
  #pragma unroll
  for (int i=0;i<4;i++){
    int c = t + i*256;
    int row = c>>4, slot = c&15;
    uint4 v = make_uint4(0,0,0,0);
    if (n0 + row < n) v = Gg[(size_t)(n0+row)*16 + slot];
    As4[row*16 + (slot^(row&7))] = v;
  }
  __syncthreads();

  int w = t>>6, l = t&63;
  int lr = l&15, lg = l>>4;
  f32x4 acc[8];
  #pragma unroll
  for (int j=0;j<8;j++) acc[j] = (f32x4){0.f,0.f,0.f,0.f};

  float bv[8];
  #pragma unroll
  for (int j=0;j<8;j++) bv[j] = b[16*j + lr];

  #pragma unroll
  for (int s=0;s<4;s++){
    short8 a = *(const short8*)&As4[(16*w + lr)*16 + ((4*s + lg)^(lr&7))];
    #pragma unroll
    for (int j=0;j<8;j++){
      short8 bb = *(const short8*)&Ws4[(16*j + lr)*16 + ((4*s + lg)^(lr&7))];
      acc[j] = __builtin_amdgcn_mfma_f32_16x16x32_bf16(a, bb, acc[j], 0, 0, 0);
    }
  }

  #pragma unroll
  for (int j=0;j<8;j++){
    int col = 16*j + lr;
    #pragma unroll
    for (int q=0;q<4;q++){
      int node = n0 + 16*w + lg*4 + q;
      if (node < n){
        float v = dis[node]*fmaxf(acc[j][q] + bv[j], 0.f);
        h[(size_t)node*HDIM + col] = f2bf(v);
      }
    }
  }
}

// ---------- mm2 fused with z: zs[node] = dis * dot(relu(g@W2+b2), Wo) ----------
__global__ __launch_bounds__(256) void k_mmz(const uint* __restrict__ g, const ushort* __restrict__ Wt,
                     const float* __restrict__ b, const float* __restrict__ Wo,
                     const float* __restrict__ dis, float* __restrict__ zs, int n){
  __shared__ uint4 Ws4[2048];
  __shared__ uint4 As4[1024];
  int t = threadIdx.x;
  int n0 = blockIdx.x*64;

  const uint4* Wg = (const uint4*)Wt;
  #pragma unroll
  for (int i=0;i<8;i++){
    int c = t + i*256;
    int row = c>>4, slot = c&15;
    Ws4[row*16 + (slot^(row&7))] = Wg[c];
  }
  const uint4* Gg = (const uint4*)g;
  #pragma unroll
  for (int i=0;i<4;i++){
    int c = t + i*256;
    int row = c>>4, slot = c&15;
    uint4 v = make_uint4(0,0,0,0);
    if (n0 + row < n) v = Gg[(size_t)(n0+row)*16 + slot];
    As4[row*16 + (slot^(row&7))] = v;
  }
  __syncthreads();

  int w = t>>6, l = t&63;
  int lr = l&15, lg = l>>4;
  f32x4 acc[8];
  #pragma unroll
  for (int j=0;j<8;j++) acc[j] = (f32x4){0.f,0.f,0.f,0.f};

  float bv[8], wo[8];
  #pragma unroll
  for (int j=0;j<8;j++){ bv[j] = b[16*j + lr]; wo[j] = Wo[16*j + lr]; }

  #pragma unroll
  for (int s=0;s<4;s++){
    short8 a = *(const short8*)&As4[(16*w + lr)*16 + ((4*s + lg)^(lr&7))];
    #pragma unroll
    for (int j=0;j<8;j++){
      short8 bb = *(const short8*)&Ws4[(16*j + lr)*16 + ((4*s + lg)^(lr&7))];
      acc[j] = __builtin_amdgcn_mfma_f32_16x16x32_bf16(a, bb, acc[j], 0, 0, 0);
    }
  }

  float zacc[4] = {0.f,0.f,0.f,0.f};
  #pragma unroll
  for (int j=0;j<8;j++){
    #pragma unroll
    for (int q=0;q<4;q++){
      float r = fmaxf(acc[j][q] + bv[j], 0.f);
      zacc[q] = fmaf(r, wo[j], zacc[q]);
    }
  }
  #pragma unroll
  for (int m=1;m<16;m<<=1){
    #pragma unroll
    for (int q=0;q<4;q++) zacc[q] += __shfl_xor(zacc[q], m);
  }
  if (lr==0){
    #pragma unroll
    for (int q=0;q<4;q++){
      int node = n0 + 16*w + lg*4 + q;
      if (node < n) zs[node] = dis[node]*zacc[q];
    }
  }
}

// ---------- y_i = sigmoid(dis_i*(zs_i + sum zs[src]) + bo) ----------
__global__ void k_final(const float* __restrict__ zs, const int* __restrict__ off, const int* __restrict__ cnt,
                        const int* __restrict__ cw, const float* __restrict__ dis,
                        const float* __restrict__ bo, float* __restrict__ y, int n){
  int i = blockIdx.x*256 + threadIdx.x;
  if (i>=n) return;
  int b = off[i], e = b + cnt[i];
  float acc = zs[i];
  int k = b;
  for (; k+4<=e; k+=4){
    int s0=cw[k], s1=cw[k+1], s2=cw[k+2], s3=cw[k+3];
    float a0=zs[s0], a1=zs[s1], a2=zs[s2], a3=zs[s3];
    acc += (a0+a1) + (a2+a3);
  }
  for (; k<e; ++k) acc += zs[cw[k]];
  float v = dis[i]*acc + bo[0];
  y[i] = 1.f/(1.f + expf(-v));
}

extern "C" void kernel_launch(void* const* d_in, const int* in_sizes, int n_in,
                              void* d_out, int out_size, void* d_ws, size_t ws_size,
                              hipStream_t stream){
  const float* x  = (const float*)d_in[0];
  const int*   ei = (const int*)d_in[1];
  const float* W0 = (const float*)d_in[2];
  const float* b0 = (const float*)d_in[3];
  const float* W1 = (const float*)d_in[4];
  const float* b1 = (const float*)d_in[5];
  const float* W2 = (const float*)d_in[6];
  const float* b2 = (const float*)d_in[7];
  const float* Wo = (const float*)d_in[8];
  const float* bo = (const float*)d_in[9];
  int n = in_sizes[0];
  int e = in_sizes[1]/2;
  const int* src = ei;
  const int* dst = ei + e;
  float* y = (float*)d_out;

  int R = (n + 7) >> 3;             // partition size (dst range per XCD)

  char* p = (char*)d_ws;
  auto alloc = [&](size_t bytes)->void*{ void* r=p; p += (bytes+255)&~(size_t)255; return r; };
  int*    cnt  = (int*)   alloc((size_t)n*4);
  int*    off  = (int*)   alloc((size_t)n*4);
  int*    cur  = (int*)   alloc((size_t)n*4);
  int*    bsum = (int*)   alloc(512*4);
  int*    bpre = (int*)   alloc(512*4);
  int*    bh   = (int*)   alloc((size_t)8*BINB*4);
  int*    bbase= (int*)   alloc((size_t)8*BINB*4);
  int*    pst  = (int*)   alloc(16*4);
  float*  dis  = (float*) alloc((size_t)n*4);
  float*  xs   = (float*) alloc((size_t)n*4);
  float*  sb   = (float*) alloc((size_t)n*4);
  float*  zb   = (float*) alloc((size_t)n*4);
  ushort* Wt1  = (ushort*)alloc((size_t)HDIM*HDIM*2);
  ushort* Wt2  = (ushort*)alloc((size_t)HDIM*HDIM*2);
  int*    cw   = (int*)   alloc((size_t)e*4);
  int2*   bins = (int2*)  alloc((size_t)e*8);
  uint*   hb0  = (uint*)  alloc((size_t)n*64*4);
  uint*   hb1  = (uint*)  alloc((size_t)n*64*4);
  uint*   gbuf = (uint*)  alloc((size_t)n*64*4);

  int nb = (n+255)/256;
  int mb = (n+63)/64;

  k_prep    <<<nb,256,0,stream>>>(cnt,W1,W2,Wt1,Wt2,n);
  k_bcnt    <<<BINB,256,0,stream>>>(dst,bh,e,R);
  k_bscan   <<<1,512,0,stream>>>(bh,bbase,pst,e);
  k_bin2    <<<BINB,256,0,stream>>>(src,dst,bbase,bins,e,R);
  k_count2  <<<512,256,0,stream>>>(bins,pst,cnt);
  k_scan1   <<<nb,256,0,stream>>>(cnt,off,bsum,dis,xs,x,n);
  k_scan2   <<<1,512,0,stream>>>(bsum,bpre,nb);
  k_scan3   <<<nb,256,0,stream>>>(off,cur,bpre,n);
  k_scatter2<<<512,256,0,stream>>>(bins,pst,cur,cw);

  k_sagg <<<nb,256,0,stream>>>(xs,dis,off,cnt,cw,sb,n);
  k_h0   <<<(n*32+255)/256,256,0,stream>>>(sb,dis,W0,b0,hb0,n);

  k_wagg <<<(n+3)/4,256,0,stream>>>(hb0,off,cnt,cw,dis,gbuf,n);
  k_mm   <<<mb,256,0,stream>>>(gbuf,Wt1,b1,dis,(ushort*)hb1,n);

  k_wagg <<<(n+3)/4,256,0,stream>>>(hb1,off,cnt,cw,dis,gbuf,n);
  k_mmz  <<<mb,256,0,stream>>>(gbuf,Wt2,b2,Wo,dis,zb,n);

  k_final<<<nb,256,0,stream>>>(zb,off,cnt,cw,dis,bo,y,n);
}